// Round 9
// baseline (2280.453 us; speedup 1.0000x reference)
//
#include <hip/hip_runtime.h>

// NeuralODE, ALL-F32 I/O.
// GRU: 512 thr, in-wave gates, 1 barrier/step, hi/lo-split MFMA chains.
// h2o MLP: f32 VALU. o2d MLP: f16 MFMA hi/lo.
// Tsit5 x255: 512 thr (8 waves, 2/SIMD), 3 barriers/feval:
//   [L1][L2+per-wave L3 partial][reduce+update+L0].
// s_x0/s_x1 row stride padded to 288 f16 so hi-row lanes hit banks 0-15 and
// lo-row lanes banks 16-31 -> broadcast ds_read_b128 is conflict-free.
// ys workspace: u32-packed f16 (hi | lo<<16) = 4 MB.

typedef unsigned short u16;
typedef unsigned int u32;
typedef _Float16 f16;
typedef __attribute__((ext_vector_type(8))) _Float16 f16x8;
typedef __attribute__((ext_vector_type(4))) float f32x4;

#define MFMA16(A, B, C) __builtin_amdgcn_mfma_f32_16x16x32_f16((A), (B), (C), 0, 0, 0)

__device__ __forceinline__ u16 f16bits(f16 h) { union { f16 f; u16 u; } c; c.f = h; return c.u; }
__device__ __forceinline__ f16 bitsf16(u16 u) { union { f16 f; u16 u; } c; c.u = u; return c.f; }
__device__ __forceinline__ void split(float v, f16& hi, f16& lo) {
    hi = (f16)v;
    lo = (f16)(v - (float)hi);
}
__device__ __forceinline__ u32 packf16(float v) {
    f16 hi, lo;
    split(v, hi, lo);
    return (u32)f16bits(hi) | ((u32)f16bits(lo) << 16);
}
__device__ __forceinline__ float fsig(float x) { return 1.0f / (1.0f + __expf(-x)); }
__device__ __forceinline__ float ftanh(float x) {
    float e = __expf(2.0f * x);
    return 1.0f - 2.0f / (e + 1.0f);
}

// Tsit5 tableau: rows 0..4 = stage-argument coefficients, row 5 = final update.
constexpr float cAc[6][6] = {
    {0.161f, 0.f, 0.f, 0.f, 0.f, 0.f},
    {-0.008480655492356989f, 0.335480655492357f, 0.f, 0.f, 0.f, 0.f},
    {2.8971530571054935f, -6.359448489975075f, 4.3622954328695815f, 0.f, 0.f, 0.f},
    {5.325864828439257f, -11.748883564062828f, 7.4955393428898365f, -0.09249506636175525f, 0.f, 0.f},
    {5.86145544294642f, -12.92096931784711f, 8.159367898576159f, -0.071584973281401f, -0.028269050394068383f, 0.f},
    {0.09646076681806523f, 0.01f, 0.4798896504144996f, 1.379008574103742f, -3.290069515436081f, 2.324710524099774f}};

// =====================================================================
// Kernel 1: GRU, 512 thr / 8 waves, in-wave gates, 1 barrier per step.
// Wave w owns gate tiles {w, w+8, w+16}. Hi/lo B-chains split (depth 5).
// =====================================================================
__global__ __launch_bounds__(512, 2) void gru_h2o_kernel(
    const float* __restrict__ yi,   // [256,256,16]
    const float* __restrict__ wih,  // [384,16]
    const float* __restrict__ whh,  // [384,128]
    const float* __restrict__ gb,   // [384]
    const float* __restrict__ gbn,  // [128]
    const float* __restrict__ hW1, const float* __restrict__ hb1,  // [256,128],[256]
    const float* __restrict__ hW2, const float* __restrict__ hb2,  // [256,256],[256]
    const float* __restrict__ hW3, const float* __restrict__ hb3,  // [32,256],[32]
    u32* __restrict__ ys)  // [256,256,32] packed f16 hi|lo; writes ys[0]
{
    const int b = blockIdx.x;
    const int tid = threadIdx.x;
    const int wave = tid >> 6;   // 0..7
    const int lane = tid & 63;
    const int quad = lane >> 4;
    const int col = lane & 15;
    const int j = wave * 16 + col;  // this lane's h-component

    // A rows: 0=(x|h)hi 1=(x|h)lo 2=(x|0)hi 3=(x|0)lo ; K=160 (16 x | 128 h | 16 pad)
    __shared__ alignas(16) f16 s_a[2][4][160];  // ping-pong
    __shared__ float s_h[128];
    __shared__ float s_t[256];

    const f32x4 ZC = {0.f, 0.f, 0.f, 0.f};

    // ---- weight fragments: tiles w, w+8, w+16 ----
    f16x8 wf[3][5][2];
#pragma unroll
    for (int tt = 0; tt < 3; ++tt) {
        const int n = (wave + tt * 8) * 16 + col;
#pragma unroll
        for (int kk = 0; kk < 5; ++kk) {
            const int k0 = kk * 32 + quad * 8;
            float w8[8];
            if (k0 < 16) {
#pragma unroll
                for (int jj = 0; jj < 8; ++jj) w8[jj] = wih[n * 16 + k0 + jj];
            } else if (k0 < 144) {
#pragma unroll
                for (int jj = 0; jj < 8; ++jj) w8[jj] = whh[n * 128 + (k0 - 16) + jj];
            } else {
#pragma unroll
                for (int jj = 0; jj < 8; ++jj) w8[jj] = 0.0f;
            }
            f16x8 hi, lo;
#pragma unroll
            for (int jj = 0; jj < 8; ++jj) {
                f16 h, l;
                split(w8[jj], h, l);
                hi[jj] = h;
                lo[jj] = l;
            }
            wf[tt][kk][0] = hi;
            wf[tt][kk][1] = lo;
        }
    }

    const float b_r = gb[j];
    const float b_z = gb[128 + j];
    const float b_c = gb[256 + j];
    const float b_n = gbn[j];

    // zero both buffers (covers pad and h-region of rows 2/3)
    for (int i = tid; i < 2 * 4 * 160; i += 512) ((f16*)s_a)[i] = (f16)0.0f;
    __syncthreads();
    if (tid < 16) {  // first x (t = 255) into buffer 0
        const float xv = yi[(size_t)b * 4096 + 255 * 16 + tid];
        f16 hi, lo;
        split(xv, hi, lo);
        s_a[0][0][tid] = hi;
        s_a[0][1][tid] = lo;
        s_a[0][2][tid] = hi;
        s_a[0][3][tid] = lo;
    }
    __syncthreads();

    float h = 0.0f;
#pragma unroll 1
    for (int ti = 0; ti < 256; ++ti) {
        const int p = ti & 1;
        const int np = 1 - p;
        // prefetch next x early (consumed after gates)
        float xnext = 0.0f;
        if (tid < 16 && ti < 255) xnext = yi[(size_t)b * 4096 + (254 - ti) * 16 + tid];

        f32x4 a0h = ZC, a0l = ZC, a1h = ZC, a1l = ZC, a2h = ZC, a2l = ZC;
#pragma unroll
        for (int kk = 0; kk < 5; ++kk) {
            const f16x8 a = *(const f16x8*)&s_a[p][col & 3][kk * 32 + quad * 8];
            a0h = MFMA16(a, wf[0][kk][0], a0h);
            a0l = MFMA16(a, wf[0][kk][1], a0l);
            a1h = MFMA16(a, wf[1][kk][0], a1h);
            a1l = MFMA16(a, wf[1][kk][1], a1l);
            a2h = MFMA16(a, wf[2][kk][0], a2h);
            a2l = MFMA16(a, wf[2][kk][1], a2l);
        }
        // gates — identical in all lanes of the wave (quads are copies)
        {
            const float sum_r = (a0h[0] + a0h[1]) + (a0l[0] + a0l[1]);
            const float sum_z = (a1h[0] + a1h[1]) + (a1l[0] + a1l[1]);
            const float sum_c = (a2h[0] + a2h[1]) + (a2l[0] + a2l[1]);  // full (x|h)
            const float icc = (a2h[2] + a2h[3]) + (a2l[2] + a2l[3]);    // x-only
            const float r = fsig(sum_r + b_r);
            const float z = fsig(sum_z + b_z);
            const float ic = icc + b_c;
            const float hn = (sum_c - icc) + b_n;
            const float nn = ftanh(ic + r * hn);
            h = nn + z * (h - nn);
        }
        if (quad == 0) {  // write h (hi/lo) for next step
            f16 hh, hl;
            split(h, hh, hl);
            s_a[np][0][16 + j] = hh;
            s_a[np][1][16 + j] = hl;
        }
        if (tid < 16 && ti < 255) {  // stage next x
            f16 hi, lo;
            split(xnext, hi, lo);
            s_a[np][0][tid] = hi;
            s_a[np][1][tid] = lo;
            s_a[np][2][tid] = hi;
            s_a[np][3][tid] = lo;
        }
        __syncthreads();
    }

    if (quad == 0) s_h[j] = h;
    __syncthreads();

    // ----- h2o MLP, f32 VALU (tid < 256) -----
    float a1v = 0.0f;
    if (tid < 256) {
        a1v = hb1[tid];
        const float* w = hW1 + (size_t)tid * 128;
#pragma unroll 8
        for (int p = 0; p < 128; ++p) a1v += w[p] * s_h[p];
        a1v = ftanh(a1v);
        s_t[tid] = a1v;
    }
    __syncthreads();
    float a2v = 0.0f;
    if (tid < 256) {
        a2v = hb2[tid];
        const float* w = hW2 + (size_t)tid * 256;
#pragma unroll 8
        for (int p = 0; p < 256; ++p) a2v += w[p] * s_t[p];
        a2v = ftanh(a2v);
    }
    __syncthreads();
    if (tid < 256) s_t[tid] = a2v;
    __syncthreads();
    if (tid < 32) {
        float a3 = hb3[tid];
        const float* w = hW3 + (size_t)tid * 256;
#pragma unroll 8
        for (int p = 0; p < 256; ++p) a3 += w[p] * s_t[p];
        ys[(size_t)b * 32 + tid] = packf16(a3);
    }
}

// =====================================================================
// Kernel 2: Tsit5, one WG (512 thr = 8 waves, 2/SIMD) per batch row.
// Wave w owns n-tiles 2w,2w+1 (outputs 32w..32w+31) for L0/L1/L2; its L3
// K-chunk = those same 32 x2 comps via per-wave LDS (no barrier).
// 3 barriers/feval. s_x0/s_x1 stride 288: hi banks 0-15, lo banks 16-31.
// =====================================================================
__global__ __launch_bounds__(512, 2) void ode_kernel(
    const float* __restrict__ ts,  // [256]
    const float* __restrict__ W0,  // [256,32]
    const float* __restrict__ W1,  // [256,256]
    const float* __restrict__ W2,  // [256,256]
    const float* __restrict__ Wo,  // [32,256]
    u32* __restrict__ ys)          // [256,256,32] packed
{
    const int b = blockIdx.x;
    const int tid = threadIdx.x;
    const int wave = tid >> 6;   // 0..7
    const int lane = tid & 63;
    const int quad = lane >> 4;
    const int col = lane & 15;
    const int half = quad >> 1;        // 0 or 1
    const int hl = quad & 1;           // 0 = hi, 1 = lo
    const int cidx = col + half * 16;  // y/k component (0..31)

    // stride 288 = 576B = 144 dwords; 144%32=16 -> lo row starts at bank 16
    __shared__ alignas(16) f16 s_x0[2][288];
    __shared__ alignas(16) f16 s_x1[2][288];
    __shared__ alignas(16) f16 s_x2w[8][2][32];  // per-wave x2 (own 32 comps)
    __shared__ alignas(16) f16 s_yw[8][2][32];   // per-wave private y
    __shared__ float s_part[8][32];
    __shared__ float s_ts[256];

    if (tid < 256) s_ts[tid] = ts[tid];

    const f32x4 ZC = {0.f, 0.f, 0.f, 0.f};

    // ---- weight fragments (per wave: n-tiles 2w, 2w+1) ----
    f16x8 w0f[2][2], w1f[2][8], w2f[2][8], wof[2][2];
#pragma unroll
    for (int tt = 0; tt < 2; ++tt) {
        const int n = (wave * 2 + tt) * 16 + col;
        {
            f16x8 hi, lo;
#pragma unroll
            for (int jj = 0; jj < 8; ++jj) {
                f16 h, l;
                split(W0[n * 32 + quad * 8 + jj], h, l);
                hi[jj] = h;
                lo[jj] = l;
            }
            w0f[tt][0] = hi;
            w0f[tt][1] = lo;
        }
#pragma unroll
        for (int kk = 0; kk < 8; ++kk) {
            f16x8 h1, h2;
#pragma unroll
            for (int jj = 0; jj < 8; ++jj) {
                h1[jj] = (f16)W1[n * 256 + kk * 32 + quad * 8 + jj];
                h2[jj] = (f16)W2[n * 256 + kk * 32 + quad * 8 + jj];
            }
            w1f[tt][kk] = h1;
            w2f[tt][kk] = h2;
        }
        // L3: Wout rows tt*16+col, K-chunk = wave*32, hi+lo
        {
            const int n3 = tt * 16 + col;
            f16x8 hi, lo;
#pragma unroll
            for (int jj = 0; jj < 8; ++jj) {
                f16 h, l;
                split(Wo[n3 * 256 + wave * 32 + quad * 8 + jj], h, l);
                hi[jj] = h;
                lo[jj] = l;
            }
            wof[tt][0] = hi;
            wof[tt][1] = lo;
        }
    }

    // ---- initial y ----
    float ybase;
    {
        const u32 p = ys[(size_t)b * 32 + cidx];
        const f16 yh = bitsf16((u16)(p & 0xffffu));
        const f16 yl = bitsf16((u16)(p >> 16));
        ybase = (float)yh + (float)yl;
        s_yw[wave][hl][cidx] = hl ? yl : yh;
    }
    float k_hist[6];
#pragma unroll
    for (int i = 0; i < 6; ++i) k_hist[i] = 0.0f;

    __syncthreads();  // s_ts ready (s_yw per-wave, DS in-order)

    // L0 from this wave's private y -> this lane's x0 component
    auto do_L0_x0 = [&]() {
        const f16x8 a = *(const f16x8*)&s_yw[wave][col & 1][quad * 8];
        f32x4 aA = MFMA16(a, w0f[0][0], ZC);
        aA = MFMA16(a, w0f[0][1], aA);
        f32x4 aB = MFMA16(a, w0f[1][0], ZC);
        aB = MFMA16(a, w0f[1][1], aB);
        const float e = half ? (aB[0] + aB[1]) : (aA[0] + aA[1]);
        const float x = ftanh(e);
        const f16 xh = (f16)x;
        s_x0[hl][(wave * 2 + half) * 16 + col] = hl ? (f16)(x - (float)xh) : xh;
    };

    do_L0_x0();
    __syncthreads();

#pragma unroll 1
    for (int t = 0; t < 255; ++t) {
        const float hstep = s_ts[t + 1] - s_ts[t];
#pragma unroll
        for (int s = 0; s < 6; ++s) {
            // ---- Seg 1: x1 = tanh(x0 @ W1^T), K=256, even/odd split chains ----
            {
                f32x4 e0 = ZC, e1 = ZC, o0 = ZC, o1 = ZC;
#pragma unroll
                for (int kk = 0; kk < 8; kk += 2) {
                    const f16x8 ae = *(const f16x8*)&s_x0[col & 1][kk * 32 + quad * 8];
                    const f16x8 ao = *(const f16x8*)&s_x0[col & 1][(kk + 1) * 32 + quad * 8];
                    e0 = MFMA16(ae, w1f[0][kk], e0);
                    e1 = MFMA16(ae, w1f[1][kk], e1);
                    o0 = MFMA16(ao, w1f[0][kk + 1], o0);
                    o1 = MFMA16(ao, w1f[1][kk + 1], o1);
                }
                const float e = half ? (e1[0] + e1[1] + o1[0] + o1[1])
                                     : (e0[0] + e0[1] + o0[0] + o0[1]);
                const float x = ftanh(e);
                const f16 xh = (f16)x;
                s_x1[hl][(wave * 2 + half) * 16 + col] = hl ? (f16)(x - (float)xh) : xh;
            }
            __syncthreads();
            // ---- Seg 2: x2 = tanh(x1 @ W2^T) -> per-wave LDS -> own L3 chunk ----
            {
                f32x4 e0 = ZC, e1 = ZC, o0 = ZC, o1 = ZC;
#pragma unroll
                for (int kk = 0; kk < 8; kk += 2) {
                    const f16x8 ae = *(const f16x8*)&s_x1[col & 1][kk * 32 + quad * 8];
                    const f16x8 ao = *(const f16x8*)&s_x1[col & 1][(kk + 1) * 32 + quad * 8];
                    e0 = MFMA16(ae, w2f[0][kk], e0);
                    e1 = MFMA16(ae, w2f[1][kk], e1);
                    o0 = MFMA16(ao, w2f[0][kk + 1], o0);
                    o1 = MFMA16(ao, w2f[1][kk + 1], o1);
                }
                const float e = half ? (e1[0] + e1[1] + o1[0] + o1[1])
                                     : (e0[0] + e0[1] + o0[0] + o0[1]);
                const float x = ftanh(e);
                const f16 xh = (f16)x;
                s_x2w[wave][hl][half * 16 + col] = hl ? (f16)(x - (float)xh) : xh;
                // L3 partial from own K-chunk (same-wave DS, no barrier)
                const f16x8 a = *(const f16x8*)&s_x2w[wave][col & 1][quad * 8];
                f32x4 p0 = MFMA16(a, wof[0][0], ZC);
                p0 = MFMA16(a, wof[0][1], p0);
                f32x4 p1 = MFMA16(a, wof[1][0], ZC);
                p1 = MFMA16(a, wof[1][1], p1);
                if (quad == 0) s_part[wave][col] = p0[0] + p0[1];
                if (quad == 1) s_part[wave][16 + col] = p1[0] + p1[1];
            }
            __syncthreads();
            // ---- Seg 3: reduce + tableau update + L0 for next argument ----
            {
                float kv = 0.0f;
#pragma unroll
                for (int p = 0; p < 8; ++p) kv += s_part[p][cidx];
                k_hist[s] = kv;
                float sum = 0.0f;
#pragma unroll
                for (int i = 0; i < 6; ++i)
                    if (i <= s) sum += cAc[s][i] * k_hist[i];
                const float v = ybase + hstep * sum;
                if (s == 5) {
                    ybase = v;
                    if (wave == 0 && !hl)
                        ys[((size_t)(t + 1) * 256 + b) * 32 + cidx] = packf16(v);
                }
                const f16 vh = (f16)v;
                s_yw[wave][hl][cidx] = hl ? (f16)(v - (float)vh) : vh;
                do_L0_x0();  // same-wave y roundtrip, DS in-order
            }
            __syncthreads();
        }
    }
}

// =====================================================================
// Kernel 3: o2d MLP (identity), f16 MFMA, (A_hi+A_lo)(B_hi+B_lo).
// 16 rows of flattened [T*B] per WG. Output f32.
// =====================================================================
__global__ __launch_bounds__(256, 1) void o2d_kernel(
    const u32* __restrict__ ys,  // [T*B, 32] packed f16 hi|lo
    const float* __restrict__ W1, const float* __restrict__ b1,  // [256,32],[256]
    const float* __restrict__ W2, const float* __restrict__ b2,  // [256,256],[256]
    const float* __restrict__ W3, const float* __restrict__ b3,  // [16,256],[16]
    float* __restrict__ out)  // [B,T,16]
{
    const int r0 = blockIdx.x * 16;
    const int tid = threadIdx.x;
    const int wave = tid >> 6;
    const int lane = tid & 63;
    const int quad = lane >> 4;
    const int col = lane & 15;

    __shared__ alignas(16) f16 s_a[2][16][32];
    __shared__ alignas(16) f16 s_x[2][2][16][264];
    __shared__ float s_part[4][16][16];

    const f32x4 ZC = {0.f, 0.f, 0.f, 0.f};

    f16x8 w1f[4][2], w2f[4][8][2], w3f[2][2];
    float b1r[4], b2r[4];
#pragma unroll
    for (int tt = 0; tt < 4; ++tt) {
        const int n = (wave * 4 + tt) * 16 + col;
        b1r[tt] = b1[n];
        b2r[tt] = b2[n];
        {
            f16x8 hi, lo;
#pragma unroll
            for (int jj = 0; jj < 8; ++jj) {
                f16 h, l;
                split(W1[n * 32 + quad * 8 + jj], h, l);
                hi[jj] = h;
                lo[jj] = l;
            }
            w1f[tt][0] = hi;
            w1f[tt][1] = lo;
        }
#pragma unroll
        for (int kk = 0; kk < 8; ++kk) {
            f16x8 hi, lo;
#pragma unroll
            for (int jj = 0; jj < 8; ++jj) {
                f16 h, l;
                split(W2[n * 256 + kk * 32 + quad * 8 + jj], h, l);
                hi[jj] = h;
                lo[jj] = l;
            }
            w2f[tt][kk][0] = hi;
            w2f[tt][kk][1] = lo;
        }
    }
#pragma unroll
    for (int c = 0; c < 2; ++c) {
        const int kk = wave * 2 + c;
        f16x8 hi, lo;
#pragma unroll
        for (int jj = 0; jj < 8; ++jj) {
            f16 h, l;
            split(W3[col * 256 + kk * 32 + quad * 8 + jj], h, l);
            hi[jj] = h;
            lo[jj] = l;
        }
        w3f[c][0] = hi;
        w3f[c][1] = lo;
    }

    {  // stage ys rows (unpack f16 hi/lo)
        const int row = tid >> 4;
        const int k2 = (tid & 15) * 2;
        const u32 p0 = ys[(size_t)(r0 + row) * 32 + k2];
        const u32 p1 = ys[(size_t)(r0 + row) * 32 + k2 + 1];
        s_a[0][row][k2] = bitsf16((u16)(p0 & 0xffffu));
        s_a[0][row][k2 + 1] = bitsf16((u16)(p1 & 0xffffu));
        s_a[1][row][k2] = bitsf16((u16)(p0 >> 16));
        s_a[1][row][k2 + 1] = bitsf16((u16)(p1 >> 16));
    }
    __syncthreads();

    f32x4 acc[4];
    // ---- L1: K=32 ----
#pragma unroll
    for (int tt = 0; tt < 4; ++tt) acc[tt] = ZC;
#pragma unroll
    for (int hl = 0; hl < 2; ++hl) {
        const f16x8 a = *(const f16x8*)&s_a[hl][col][quad * 8];
#pragma unroll
        for (int bl = 0; bl < 2; ++bl)
#pragma unroll
            for (int tt = 0; tt < 4; ++tt) acc[tt] = MFMA16(a, w1f[tt][bl], acc[tt]);
    }
#pragma unroll
    for (int tt = 0; tt < 4; ++tt) {
        const int n = (wave * 4 + tt) * 16 + col;
#pragma unroll
        for (int rg = 0; rg < 4; ++rg) {
            const int row = quad * 4 + rg;
            const float v = acc[tt][rg] + b1r[tt];
            f16 hi, lo;
            split(v, hi, lo);
            s_x[0][0][row][n] = hi;
            s_x[0][1][row][n] = lo;
        }
    }
    __syncthreads();
    // ---- L2: K=256 ----
#pragma unroll
    for (int tt = 0; tt < 4; ++tt) acc[tt] = ZC;
#pragma unroll
    for (int kk = 0; kk < 8; ++kk) {
#pragma unroll
        for (int hl = 0; hl < 2; ++hl) {
            const f16x8 a = *(const f16x8*)&s_x[0][hl][col][kk * 32 + quad * 8];
#pragma unroll
            for (int bl = 0; bl < 2; ++bl)
#pragma unroll
                for (int tt = 0; tt < 4; ++tt) acc[tt] = MFMA16(a, w2f[tt][kk][bl], acc[tt]);
        }
    }
#pragma unroll
    for (int tt = 0; tt < 4; ++tt) {
        const int n = (wave * 4 + tt) * 16 + col;
#pragma unroll
        for (int rg = 0; rg < 4; ++rg) {
            const int row = quad * 4 + rg;
            const float v = acc[tt][rg] + b2r[tt];
            f16 hi, lo;
            split(v, hi, lo);
            s_x[1][0][row][n] = hi;
            s_x[1][1][row][n] = lo;
        }
    }
    __syncthreads();
    // ---- L3: N=16, K split over waves ----
    f32x4 a3 = ZC;
#pragma unroll
    for (int c = 0; c < 2; ++c) {
        const int kk = wave * 2 + c;
#pragma unroll
        for (int hl = 0; hl < 2; ++hl) {
            const f16x8 a = *(const f16x8*)&s_x[1][hl][col][kk * 32 + quad * 8];
#pragma unroll
            for (int bl = 0; bl < 2; ++bl) a3 = MFMA16(a, w3f[c][bl], a3);
        }
    }
#pragma unroll
    for (int rg = 0; rg < 4; ++rg) s_part[wave][quad * 4 + rg][col] = a3[rg];
    __syncthreads();
    {
        const int row = tid >> 4;
        const int cc = tid & 15;
        const float v = s_part[0][row][cc] + s_part[1][row][cc] + s_part[2][row][cc] +
                        s_part[3][row][cc] + b3[cc];
        const int r = r0 + row;
        const int bb = r & 255;   // batch index
        const int tt2 = r >> 8;   // time index
        out[((size_t)bb * 256 + tt2) * 16 + cc] = v;
    }
}

// =====================================================================
extern "C" void kernel_launch(void* const* d_in, const int* in_sizes, int n_in,
                              void* d_out, int out_size, void* d_ws, size_t ws_size,
                              hipStream_t stream) {
    (void)in_sizes; (void)n_in; (void)out_size; (void)ws_size;
    const float* ts      = (const float*)d_in[0];
    const float* yi      = (const float*)d_in[1];
    const float* gru_wih = (const float*)d_in[2];
    const float* gru_whh = (const float*)d_in[3];
    const float* gru_b   = (const float*)d_in[4];
    const float* gru_bn  = (const float*)d_in[5];
    const float* h2o_W1  = (const float*)d_in[6];
    const float* h2o_b1  = (const float*)d_in[7];
    const float* h2o_W2  = (const float*)d_in[8];
    const float* h2o_b2  = (const float*)d_in[9];
    const float* h2o_W3  = (const float*)d_in[10];
    const float* h2o_b3  = (const float*)d_in[11];
    const float* cf_W0   = (const float*)d_in[12];
    const float* cf_W1   = (const float*)d_in[13];
    const float* cf_W2   = (const float*)d_in[14];
    const float* cf_Wout = (const float*)d_in[15];
    const float* o2d_W1  = (const float*)d_in[16];
    const float* o2d_b1  = (const float*)d_in[17];
    const float* o2d_W2  = (const float*)d_in[18];
    const float* o2d_b2  = (const float*)d_in[19];
    const float* o2d_W3  = (const float*)d_in[20];
    const float* o2d_b3  = (const float*)d_in[21];

    u32* ys = (u32*)d_ws;  // [256,256,32] packed f16 (hi | lo<<16) = 4 MB

    gru_h2o_kernel<<<256, 512, 0, stream>>>(yi, gru_wih, gru_whh, gru_b, gru_bn,
                                            h2o_W1, h2o_b1, h2o_W2, h2o_b2, h2o_W3, h2o_b3, ys);
    ode_kernel<<<256, 512, 0, stream>>>(ts, cf_W0, cf_W1, cf_W2, cf_Wout, ys);
    o2d_kernel<<<4096, 256, 0, stream>>>(ys, o2d_W1, o2d_b1, o2d_W2, o2d_b2,
                                         o2d_W3, o2d_b3, (float*)d_out);
}